// Round 9
// baseline (284.167 us; speedup 1.0000x reference)
//
#include <hip/hip_runtime.h>

#define ZD 64
#define RD 128
#define HIDDEN 512
#define NSTEP 100
#define OUT_PITCH 6464              // 101*64
#define DT_F 0.01f
#define ROWS 16

static const size_t LW_OFF = 52953088ull;   // 8192*101*64
static const size_t NG_OFF = 52961280ull;   // + 8192

typedef __attribute__((ext_vector_type(2))) float  f32x2;
typedef __attribute__((ext_vector_type(4))) float  f32x4;
typedef __attribute__((ext_vector_type(8))) __bf16 bf16x8;
typedef __attribute__((ext_vector_type(2))) short  s16x2;
typedef __attribute__((ext_vector_type(4))) short  s16x4;
typedef __attribute__((ext_vector_type(8))) short  s16x8;

__device__ __forceinline__ short f2bs(float f) {
    return __builtin_bit_cast(short, (__bf16)f);
}
__device__ __forceinline__ float bs2f(short s) {
    return __builtin_bit_cast(float, ((unsigned)(unsigned short)s) << 16);
}
__device__ __forceinline__ float tanh_fast(float x) {
    float e = __builtin_amdgcn_exp2f(x * 2.88539008177793f);
    float r = __builtin_amdgcn_rcpf(e + 1.0f);
    return fmaf(-2.0f, r, 1.0f);
}

// ---------------------------------------------------------------------------
// sim_kernel: persistent scan. 512 blocks x 512 threads (8 waves), 16 rows
// -> TWO co-resident blocks/CU that drift out of phase and fill each other's
// pipe bubbles (R8's single 16-wave block was phase-lockstep at ~50% DS and
// ~50% VALU). Register diet keeps combined VGPR+AGPR <= 128: w1f 32 + w2f 32
// + pref packed bf16 8 = ~80 persistent.
// GEMM1: 8 waves x 4 n-tiles x 1 m-tile. GEMM2: (z-half x K-quarter), each
// Hs read feeds 2 MFMAs; Ps[4] partials (stride 72), summed in update.
// ---------------------------------------------------------------------------
__global__ __launch_bounds__(512, 2)
void sim_kernel(
    const float* __restrict__ r, const float* __restrict__ noises,
    const float* __restrict__ x0, const float* __restrict__ W1,
    const float* __restrict__ b1, const float* __restrict__ W2,
    const float* __restrict__ b2, const float* __restrict__ bmax,
    const float* __restrict__ bmin, const float* __restrict__ mu,
    float* __restrict__ out)
{
    __shared__ float Ps[4][ROWS][72];                 // 18432 B
    __shared__ unsigned short Xb[ROWS * 64];          // 2048 B
    __shared__ unsigned short Hs[ROWS * HIDDEN];      // 16384 B
    __shared__ float w1ts[HIDDEN];                    // 2048 B
    __shared__ float tT[NSTEP], tG[NSTEP], tSd[NSTEP], tCd[NSTEP], tCs[NSTEP]; // 2000 B

    const int tid  = threadIdx.x;
    const int lane = tid & 63;
    const int wave = tid >> 6;       // 0..7
    const int g4   = lane >> 4;      // 0..3
    const int l16  = lane & 15;
    const int row0 = blockIdx.x * ROWS;

    // ---- step tables ----
    if (tid < NSTEP) {
        float spmax = log1pf(expf(bmax[0]));
        float spmin = log1pf(expf(bmin[0]));
        float a_ = spmax - spmin;
        float c_ = spmin;
        const float PI_ = 3.14159265358979323846f;
        float k = (float)tid;
        float t0 = k * DT_F, t1 = (k + 1.0f) * DT_F;
        float inv2pi = 1.0f / (2.0f * PI_);
        float F0 = a_ * sinf(PI_ * t0) * inv2pi + (0.5f * a_ + c_) * t0;
        float F1 = a_ * sinf(PI_ * t1) * inv2pi + (0.5f * a_ + c_) * t1;
        float al = 1.0f - expf(-2.0f * (F1 - F0));
        float gg = 1.0f - sqrtf(1.0f - al);
        float kap = (gg * gg) / al;
        tT[tid] = t0; tG[tid] = gg; tSd[tid] = sqrtf(al);
        tCd[tid] = -2.0f * kap; tCs[tid] = -2.0f * sqrtf(kap);
    }
    w1ts[tid] = W1[(size_t)192 * HIDDEN + tid];

    // ---- x state init (update-thread registers) + x_t[:,0,:] + Xb ----
    const int urow = tid >> 5;          // 0..15
    const int c2   = (tid & 31) * 2;    // 0..62
    const size_t ubase = (size_t)(row0 + urow);
    float xr0, xr1;
    {
        f32x2 v = *(const f32x2*)(x0 + ubase * ZD + c2);
        xr0 = v[0]; xr1 = v[1];
        *(f32x2*)(out + ubase * OUT_PITCH + c2) = v;
        s16x2 xv; xv[0] = f2bs(xr0); xv[1] = f2bs(xr1);
        *(s16x2*)(Xb + ((urow * 64 + c2) ^ ((urow & 7) << 3))) = xv;
    }
    const float bb0 = b2[c2], bb1 = b2[c2 + 1];

    // ---- pre-fragments via MFMA: pref = b1 + r @ W1r, packed to bf16 ----
    s16x4 prefb[4];
    {
        bf16x8 rf[4];
        const float* rp = r + (size_t)(row0 + l16) * RD;
        #pragma unroll
        for (int kc = 0; kc < 4; ++kc) {
            f32x4 lo = *(const f32x4*)(rp + kc * 32 + g4 * 8);
            f32x4 hi = *(const f32x4*)(rp + kc * 32 + g4 * 8 + 4);
            bf16x8 v;
            v[0]=(__bf16)lo[0]; v[1]=(__bf16)lo[1]; v[2]=(__bf16)lo[2]; v[3]=(__bf16)lo[3];
            v[4]=(__bf16)hi[0]; v[5]=(__bf16)hi[1]; v[6]=(__bf16)hi[2]; v[7]=(__bf16)hi[3];
            rf[kc] = v;
        }
        #pragma unroll
        for (int j2 = 0; j2 < 4; ++j2) {
            int n  = (wave * 4 + j2) * 16 + l16;
            int n0 = (wave * 4 + j2) * 16 + g4 * 4;
            f32x4 acc = *(const f32x4*)(b1 + n0);
            #pragma unroll
            for (int kc = 0; kc < 4; ++kc) {
                bf16x8 w;
                #pragma unroll
                for (int j = 0; j < 8; ++j)
                    w[j] = (__bf16)W1[(size_t)(64 + kc * 32 + g4 * 8 + j) * HIDDEN + n];
                acc = __builtin_amdgcn_mfma_f32_16x16x32_bf16(w, rf[kc], acc, 0, 0, 0);
            }
            s16x4 pb;
            pb[0] = f2bs(acc[0]); pb[1] = f2bs(acc[1]);
            pb[2] = f2bs(acc[2]); pb[3] = f2bs(acc[3]);
            prefb[j2] = pb;
        }
    }

    // ---- persistent weight fragments ----
    bf16x8 w1f[4][2];                // [j2][kc]
    #pragma unroll
    for (int j2 = 0; j2 < 4; ++j2) {
        int n = (wave * 4 + j2) * 16 + l16;
        #pragma unroll
        for (int kc = 0; kc < 2; ++kc) {
            bf16x8 v;
            #pragma unroll
            for (int j = 0; j < 8; ++j)
                v[j] = (__bf16)W1[(size_t)(kc * 32 + g4 * 8 + j) * HIDDEN + n];
            w1f[j2][kc] = v;
        }
    }
    // GEMM2 roles: zh = wave&1 (z-half), kq = wave>>1 (K-quarter).
    const int zh = wave & 1, kq = wave >> 1;
    bf16x8 w2f[2][4];
    #pragma unroll
    for (int zt2 = 0; zt2 < 2; ++zt2) {
        int n = (zh * 2 + zt2) * 16 + l16;
        #pragma unroll
        for (int i = 0; i < 4; ++i) {
            bf16x8 v;
            #pragma unroll
            for (int j = 0; j < 8; ++j)
                v[j] = (__bf16)W2[(size_t)(kq * 128 + i * 32 + g4 * 8 + j) * ZD + n];
            w2f[zt2][i] = v;
        }
    }

    float lwacc = 0.0f;
    const int xswz = (l16 & 7) << 3;

    __syncthreads();

    for (int s = 0; s < NSTEP; ++s) {
        float t = tT[s];
        // noise prefetch for update phase (hidden under 2 barriers)
        f32x2 nz = *(const f32x2*)(noises + (ubase * NSTEP + s) * ZD + c2);

        // ================= GEMM1: h = tanh(x@W1x + pre + t*w1t) ============
        {
            s16x8 xb0 = *(const s16x8*)(Xb + ((l16 * 64 + g4 * 8) ^ xswz));
            s16x8 xb1 = *(const s16x8*)(Xb + ((l16 * 64 + 32 + g4 * 8) ^ xswz));
            #pragma unroll
            for (int j2 = 0; j2 < 4; ++j2) {
                int n0 = (wave * 4 + j2) * 16 + g4 * 4;
                f32x4 wt = *(const f32x4*)(w1ts + n0);
                s16x4 pb = prefb[j2];
                f32x4 acc;
                acc[0] = fmaf(t, wt[0], bs2f(pb[0]));
                acc[1] = fmaf(t, wt[1], bs2f(pb[1]));
                acc[2] = fmaf(t, wt[2], bs2f(pb[2]));
                acc[3] = fmaf(t, wt[3], bs2f(pb[3]));
                acc = __builtin_amdgcn_mfma_f32_16x16x32_bf16(
                    w1f[j2][0], __builtin_bit_cast(bf16x8, xb0), acc, 0, 0, 0);
                acc = __builtin_amdgcn_mfma_f32_16x16x32_bf16(
                    w1f[j2][1], __builtin_bit_cast(bf16x8, xb1), acc, 0, 0, 0);
                s16x4 hv;
                hv[0] = f2bs(tanh_fast(acc[0]));
                hv[1] = f2bs(tanh_fast(acc[1]));
                hv[2] = f2bs(tanh_fast(acc[2]));
                hv[3] = f2bs(tanh_fast(acc[3]));
                *(s16x4*)(Hs + ((l16 * HIDDEN + n0) ^ xswz)) = hv;
            }
        }
        __syncthreads();

        // ====== GEMM2 (z-half x K-quarter): partials -> Ps[kq] =============
        {
            int base = l16 * HIDDEN + kq * 128 + g4 * 8;
            f32x4 aA = { 0.f, 0.f, 0.f, 0.f };
            f32x4 aB = { 0.f, 0.f, 0.f, 0.f };
            #pragma unroll
            for (int i = 0; i < 4; ++i) {
                s16x8 h = *(const s16x8*)(Hs + ((base + i * 32) ^ xswz));
                aA = __builtin_amdgcn_mfma_f32_16x16x32_bf16(
                    w2f[0][i], __builtin_bit_cast(bf16x8, h), aA, 0, 0, 0);
                aB = __builtin_amdgcn_mfma_f32_16x16x32_bf16(
                    w2f[1][i], __builtin_bit_cast(bf16x8, h), aB, 0, 0, 0);
            }
            *(f32x4*)(&Ps[kq][l16][(zh * 2 + 0) * 16 + g4 * 4]) = aA;
            *(f32x4*)(&Ps[kq][l16][(zh * 2 + 1) * 16 + g4 * 4]) = aB;
        }
        __syncthreads();

        // ================= Update (x in registers, lw deferred) ============
        {
            float gg = tG[s], sdv = tSd[s], cd = tCd[s], cs = tCs[s];
            f32x2 p0 = *(const f32x2*)(&Ps[0][urow][c2]);
            f32x2 p1 = *(const f32x2*)(&Ps[1][urow][c2]);
            f32x2 p2 = *(const f32x2*)(&Ps[2][urow][c2]);
            f32x2 p3 = *(const f32x2*)(&Ps[3][urow][c2]);
            float s0 = ((p0[0] + p1[0]) + (p2[0] + p3[0])) + bb0;
            float s1 = ((p0[1] + p1[1]) + (p2[1] + p3[1])) + bb1;
            float xn0 = xr0 + gg * (2.0f * s0 - xr0) + sdv * nz[0];
            float xn1 = xr1 + gg * (2.0f * s1 - xr1) + sdv * nz[1];
            xr0 = xn0; xr1 = xn1;
            f32x2 xv = { xn0, xn1 };
            *(f32x2*)(out + ubase * OUT_PITCH + (size_t)(s + 1) * ZD + c2) = xv;
            s16x2 xb2; xb2[0] = f2bs(xn0); xb2[1] = f2bs(xn1);
            *(s16x2*)(Xb + ((urow * 64 + c2) ^ ((urow & 7) << 3))) = xb2;
            lwacc += cd * (s0 * s0 + s1 * s1) + cs * (s0 * nz[0] + s1 * nz[1]);
        }
        __syncthreads();
    }

    // ---- finalize: log_weights and nabla_g ----
    {
        float m0 = mu[c2], m1 = mu[c2 + 1];
        float d0 = xr0 - m0, d1 = xr1 - m1;
        f32x2 ng = { d0 - xr0, d1 - xr1 };           // == -mu
        *(f32x2*)(out + NG_OFF + ubase * ZD + c2) = ng;
        float part = lwacc
                   + 0.5f * (xr0 * xr0 + xr1 * xr1) - 0.5f * (d0 * d0 + d1 * d1);
        part += __shfl_xor(part, 1, 64);
        part += __shfl_xor(part, 2, 64);
        part += __shfl_xor(part, 4, 64);
        part += __shfl_xor(part, 8, 64);
        part += __shfl_xor(part, 16, 64);
        if ((tid & 31) == 0) out[LW_OFF + ubase] = part;
    }
}

extern "C" void kernel_launch(void* const* d_in, const int* in_sizes, int n_in,
                              void* d_out, int out_size, void* d_ws, size_t ws_size,
                              hipStream_t stream) {
    const float* r      = (const float*)d_in[0];
    const float* noises = (const float*)d_in[1];
    const float* x0     = (const float*)d_in[2];
    const float* W1     = (const float*)d_in[3];
    const float* b1     = (const float*)d_in[4];
    const float* W2     = (const float*)d_in[5];
    const float* b2     = (const float*)d_in[6];
    const float* bmax   = (const float*)d_in[7];
    const float* bmin   = (const float*)d_in[8];
    const float* mu     = (const float*)d_in[9];
    float* out = (float*)d_out;

    sim_kernel<<<512, 512, 0, stream>>>(r, noises, x0, W1, b1, W2, b2,
                                        bmax, bmin, mu, out);
}

// Round 10
// 255.565 us; speedup vs baseline: 1.1119x; 1.1119x over previous
//
#include <hip/hip_runtime.h>

#define ZD 64
#define RD 128
#define HIDDEN 512
#define NSTEP 100
#define OUT_PITCH 6464              // 101*64
#define DT_F 0.01f

static const size_t LW_OFF = 52953088ull;   // 8192*101*64
static const size_t NG_OFF = 52961280ull;   // + 8192

typedef __attribute__((ext_vector_type(4))) float  f32x4;
typedef __attribute__((ext_vector_type(8))) __bf16 bf16x8;
typedef __attribute__((ext_vector_type(4))) short  s16x4;
typedef __attribute__((ext_vector_type(8))) short  s16x8;

__device__ __forceinline__ short f2bs(float f) {
    return __builtin_bit_cast(short, (__bf16)f);
}
__device__ __forceinline__ float bs2f(short s) {
    return __builtin_bit_cast(float, ((unsigned)(unsigned short)s) << 16);
}
__device__ __forceinline__ float tanh_fast(float x) {
    float e = __builtin_amdgcn_exp2f(x * 2.88539008177793f);
    float r = __builtin_amdgcn_rcpf(e + 1.0f);
    return fmaf(-2.0f, r, 1.0f);
}

// ---------------------------------------------------------------------------
// sim_kernel: persistent scan, half-pipelined. 256 blocks x 1024 threads
// (16 waves), 32 rows/block (halves A/B of 16), 1 block/CU, 4 waves/SIMD.
// Phase schedule (3 barriers/step, every phase mixes DS-heavy + VALU-heavy):
//   ph1: G2(A,s)   || G1(B,s)
//   ph2: U(A,s)    || G2(B,s)
//   ph3: U(B,s)    || G1(A,s+1)
// Per-wave roles: G1 = 2 n-tiles (w1f 16 regs, w1t in regs); G2 = (zq,kq)
// z-tile x K-quarter (w2f 16 regs); U row = wave, col = lane.
// Persistent regs ~70 -> combined VGPR+AGPR ~105 < 128 (no spills).
// ---------------------------------------------------------------------------
__global__ __launch_bounds__(1024, 1)
void sim_kernel(
    const float* __restrict__ r, const float* __restrict__ noises,
    const float* __restrict__ x0, const float* __restrict__ W1,
    const float* __restrict__ b1, const float* __restrict__ W2,
    const float* __restrict__ b2, const float* __restrict__ bmax,
    const float* __restrict__ bmin, const float* __restrict__ mu,
    float* __restrict__ out)
{
    __shared__ unsigned short XbA[16 * 64], XbB[16 * 64];      // 2048 B each
    __shared__ unsigned short HsA[16 * HIDDEN], HsB[16 * HIDDEN]; // 16384 B each
    __shared__ float PsA[4][16][76], PsB[4][16][76];           // 19456 B each
    __shared__ float tT[NSTEP], tG[NSTEP], tSd[NSTEP], tCd[NSTEP], tCs[NSTEP];

    const int tid  = threadIdx.x;
    const int lane = tid & 63;
    const int wave = tid >> 6;       // 0..15
    const int g4   = lane >> 4;      // 0..3
    const int l16  = lane & 15;
    const int row0 = blockIdx.x * 32;
    const int xswz = (l16 & 7) << 3;
    const int zq = wave & 3, kq = wave >> 2;    // GEMM2 roles

    // ---- step tables ----
    if (tid < NSTEP) {
        float spmax = log1pf(expf(bmax[0]));
        float spmin = log1pf(expf(bmin[0]));
        float a_ = spmax - spmin;
        float c_ = spmin;
        const float PI_ = 3.14159265358979323846f;
        float k = (float)tid;
        float t0 = k * DT_F, t1 = (k + 1.0f) * DT_F;
        float inv2pi = 1.0f / (2.0f * PI_);
        float F0 = a_ * sinf(PI_ * t0) * inv2pi + (0.5f * a_ + c_) * t0;
        float F1 = a_ * sinf(PI_ * t1) * inv2pi + (0.5f * a_ + c_) * t1;
        float al = 1.0f - expf(-2.0f * (F1 - F0));
        float gg = 1.0f - sqrtf(1.0f - al);
        float kap = (gg * gg) / al;
        tT[tid] = t0; tG[tid] = gg; tSd[tid] = sqrtf(al);
        tCd[tid] = -2.0f * kap; tCs[tid] = -2.0f * sqrtf(kap);
    }

    // ---- x state init (U-thread registers: row=wave, col=lane) ----
    float xA, xB, lwA = 0.f, lwB = 0.f;
    {
        xA = x0[(size_t)(row0 + wave) * ZD + lane];
        out[(size_t)(row0 + wave) * OUT_PITCH + lane] = xA;
        XbA[(wave * 64 + lane) ^ ((wave & 7) << 3)] = (unsigned short)f2bs(xA);
        xB = x0[(size_t)(row0 + 16 + wave) * ZD + lane];
        out[(size_t)(row0 + 16 + wave) * OUT_PITCH + lane] = xB;
        XbB[(wave * 64 + lane) ^ ((wave & 7) << 3)] = (unsigned short)f2bs(xB);
    }
    const float bcol = b2[lane];

    // ---- pre-fragments via MFMA: prefb[half][j2] = bf16(b1 + r @ W1r) ----
    s16x4 prefb[2][2];
    #pragma unroll
    for (int h = 0; h < 2; ++h) {
        bf16x8 rf[4];
        const float* rp = r + (size_t)(row0 + h * 16 + l16) * RD;
        #pragma unroll
        for (int kc = 0; kc < 4; ++kc) {
            f32x4 lo = *(const f32x4*)(rp + kc * 32 + g4 * 8);
            f32x4 hi = *(const f32x4*)(rp + kc * 32 + g4 * 8 + 4);
            bf16x8 v;
            v[0]=(__bf16)lo[0]; v[1]=(__bf16)lo[1]; v[2]=(__bf16)lo[2]; v[3]=(__bf16)lo[3];
            v[4]=(__bf16)hi[0]; v[5]=(__bf16)hi[1]; v[6]=(__bf16)hi[2]; v[7]=(__bf16)hi[3];
            rf[kc] = v;
        }
        #pragma unroll
        for (int j2 = 0; j2 < 2; ++j2) {
            int n  = (wave * 2 + j2) * 16 + l16;
            int n0 = (wave * 2 + j2) * 16 + g4 * 4;
            f32x4 acc = *(const f32x4*)(b1 + n0);
            #pragma unroll
            for (int kc = 0; kc < 4; ++kc) {
                bf16x8 w;
                #pragma unroll
                for (int j = 0; j < 8; ++j)
                    w[j] = (__bf16)W1[(size_t)(64 + kc * 32 + g4 * 8 + j) * HIDDEN + n];
                acc = __builtin_amdgcn_mfma_f32_16x16x32_bf16(w, rf[kc], acc, 0, 0, 0);
            }
            s16x4 pb;
            pb[0] = f2bs(acc[0]); pb[1] = f2bs(acc[1]);
            pb[2] = f2bs(acc[2]); pb[3] = f2bs(acc[3]);
            prefb[h][j2] = pb;
        }
    }

    // ---- persistent weight fragments (registers) ----
    bf16x8 w1f[2][2];     // [j2][kc]
    f32x4  w1tr[2];       // t-row of W1, per j2
    #pragma unroll
    for (int j2 = 0; j2 < 2; ++j2) {
        int n  = (wave * 2 + j2) * 16 + l16;
        int n0 = (wave * 2 + j2) * 16 + g4 * 4;
        w1tr[j2] = *(const f32x4*)(W1 + (size_t)192 * HIDDEN + n0);
        #pragma unroll
        for (int kc = 0; kc < 2; ++kc) {
            bf16x8 v;
            #pragma unroll
            for (int j = 0; j < 8; ++j)
                v[j] = (__bf16)W1[(size_t)(kc * 32 + g4 * 8 + j) * HIDDEN + n];
            w1f[j2][kc] = v;
        }
    }
    bf16x8 w2f[4];        // z-tile zq, K-quarter kq
    {
        int n2 = zq * 16 + l16;
        #pragma unroll
        for (int i = 0; i < 4; ++i) {
            bf16x8 v;
            #pragma unroll
            for (int j = 0; j < 8; ++j)
                v[j] = (__bf16)W2[(size_t)(kq * 128 + i * 32 + g4 * 8 + j) * ZD + n2];
            w2f[i] = v;
        }
    }

    // ---- phase lambdas (register arrays passed by value / static index) ----
    auto G1 = [&](const unsigned short* Xbh, unsigned short* Hsh,
                  s16x4 pb0, s16x4 pb1, float t) {
        s16x8 xb0 = *(const s16x8*)(Xbh + ((l16 * 64 + g4 * 8) ^ xswz));
        s16x8 xb1 = *(const s16x8*)(Xbh + ((l16 * 64 + 32 + g4 * 8) ^ xswz));
        #pragma unroll
        for (int j2 = 0; j2 < 2; ++j2) {
            int n0 = (wave * 2 + j2) * 16 + g4 * 4;
            s16x4 pb = j2 ? pb1 : pb0;
            f32x4 acc;
            acc[0] = fmaf(t, w1tr[j2][0], bs2f(pb[0]));
            acc[1] = fmaf(t, w1tr[j2][1], bs2f(pb[1]));
            acc[2] = fmaf(t, w1tr[j2][2], bs2f(pb[2]));
            acc[3] = fmaf(t, w1tr[j2][3], bs2f(pb[3]));
            acc = __builtin_amdgcn_mfma_f32_16x16x32_bf16(
                w1f[j2][0], __builtin_bit_cast(bf16x8, xb0), acc, 0, 0, 0);
            acc = __builtin_amdgcn_mfma_f32_16x16x32_bf16(
                w1f[j2][1], __builtin_bit_cast(bf16x8, xb1), acc, 0, 0, 0);
            s16x4 hv;
            hv[0] = f2bs(tanh_fast(acc[0]));
            hv[1] = f2bs(tanh_fast(acc[1]));
            hv[2] = f2bs(tanh_fast(acc[2]));
            hv[3] = f2bs(tanh_fast(acc[3]));
            *(s16x4*)(Hsh + ((l16 * HIDDEN + n0) ^ xswz)) = hv;
        }
    };
    auto G2 = [&](const unsigned short* Hsh, float (*Psh)[16][76]) {
        int base = l16 * HIDDEN + kq * 128 + g4 * 8;
        s16x8 h0 = *(const s16x8*)(Hsh + ((base +  0) ^ xswz));
        s16x8 h1 = *(const s16x8*)(Hsh + ((base + 32) ^ xswz));
        s16x8 h2 = *(const s16x8*)(Hsh + ((base + 64) ^ xswz));
        s16x8 h3 = *(const s16x8*)(Hsh + ((base + 96) ^ xswz));
        f32x4 a0 = { 0.f, 0.f, 0.f, 0.f };
        f32x4 a1 = { 0.f, 0.f, 0.f, 0.f };
        a0 = __builtin_amdgcn_mfma_f32_16x16x32_bf16(
            w2f[0], __builtin_bit_cast(bf16x8, h0), a0, 0, 0, 0);
        a1 = __builtin_amdgcn_mfma_f32_16x16x32_bf16(
            w2f[1], __builtin_bit_cast(bf16x8, h1), a1, 0, 0, 0);
        a0 = __builtin_amdgcn_mfma_f32_16x16x32_bf16(
            w2f[2], __builtin_bit_cast(bf16x8, h2), a0, 0, 0, 0);
        a1 = __builtin_amdgcn_mfma_f32_16x16x32_bf16(
            w2f[3], __builtin_bit_cast(bf16x8, h3), a1, 0, 0, 0);
        a0[0] += a1[0]; a0[1] += a1[1]; a0[2] += a1[2]; a0[3] += a1[3];
        *(f32x4*)(&Psh[kq][l16][zq * 16 + g4 * 4]) = a0;
    };
    auto UP = [&](float (*Psh)[16][76], unsigned short* Xbh,
                  float& xr, float& lw, float nzv, int s, int hofs) {
        float gg = tG[s], sdv = tSd[s], cd = tCd[s], cs = tCs[s];
        float sv = ((Psh[0][wave][lane] + Psh[1][wave][lane])
                  + (Psh[2][wave][lane] + Psh[3][wave][lane])) + bcol;
        float xn = xr + gg * (2.0f * sv - xr) + sdv * nzv;
        out[(size_t)(row0 + hofs + wave) * OUT_PITCH + (size_t)(s + 1) * ZD + lane] = xn;
        Xbh[(wave * 64 + lane) ^ ((wave & 7) << 3)] = (unsigned short)f2bs(xn);
        lw += cd * sv * sv + cs * sv * nzv;
        xr = xn;
    };

    __syncthreads();

    G1(XbA, HsA, prefb[0][0], prefb[0][1], tT[0]);
    __syncthreads();

    for (int s = 0; s < NSTEP; ++s) {
        float nzA = noises[((size_t)(row0 + wave) * NSTEP + s) * ZD + lane];
        G2(HsA, PsA);
        G1(XbB, HsB, prefb[1][0], prefb[1][1], tT[s]);
        __syncthreads();

        float nzB = noises[((size_t)(row0 + 16 + wave) * NSTEP + s) * ZD + lane];
        UP(PsA, XbA, xA, lwA, nzA, s, 0);
        G2(HsB, PsB);
        __syncthreads();

        UP(PsB, XbB, xB, lwB, nzB, s, 16);
        if (s + 1 < NSTEP) G1(XbA, HsA, prefb[0][0], prefb[0][1], tT[s + 1]);
        __syncthreads();
    }

    // ---- finalize: log_weights and nabla_g ----
    {
        float m = mu[lane];
        float dA = xA - m, dB = xB - m;
        out[NG_OFF + (size_t)(row0 + wave) * ZD + lane] = dA - xA;        // == -mu
        out[NG_OFF + (size_t)(row0 + 16 + wave) * ZD + lane] = dB - xB;
        float pA = lwA + 0.5f * xA * xA - 0.5f * dA * dA;
        float pB = lwB + 0.5f * xB * xB - 0.5f * dB * dB;
        #pragma unroll
        for (int o = 1; o < 64; o <<= 1) {
            pA += __shfl_xor(pA, o, 64);
            pB += __shfl_xor(pB, o, 64);
        }
        if (lane == 0) {
            out[LW_OFF + row0 + wave] = pA;
            out[LW_OFF + row0 + 16 + wave] = pB;
        }
    }
}

extern "C" void kernel_launch(void* const* d_in, const int* in_sizes, int n_in,
                              void* d_out, int out_size, void* d_ws, size_t ws_size,
                              hipStream_t stream) {
    const float* r      = (const float*)d_in[0];
    const float* noises = (const float*)d_in[1];
    const float* x0     = (const float*)d_in[2];
    const float* W1     = (const float*)d_in[3];
    const float* b1     = (const float*)d_in[4];
    const float* W2     = (const float*)d_in[5];
    const float* b2     = (const float*)d_in[6];
    const float* bmax   = (const float*)d_in[7];
    const float* bmin   = (const float*)d_in[8];
    const float* mu     = (const float*)d_in[9];
    float* out = (float*)d_out;

    sim_kernel<<<256, 1024, 0, stream>>>(r, noises, x0, W1, b1, W2, b2,
                                         bmax, bmin, mu, out);
}